// Round 7
// baseline (219.075 us; speedup 1.0000x reference)
//
#include <hip/hip_runtime.h>
#include <math.h>

#define B_ 2
#define W_ 2048
#define C_ 1024
#define H_ 16
#define K_ 64
#define LN_EPS 1e-5f

typedef __attribute__((ext_vector_type(8))) short short8;   // 8 bf16 (4 VGPRs)
typedef __attribute__((ext_vector_type(4))) float float4v;  // MFMA C/D frag

#if __has_builtin(__builtin_amdgcn_exp2f)
#define EXP2(x) __builtin_amdgcn_exp2f(x)
#else
#define EXP2(x) exp2f(x)
#endif

__device__ inline unsigned short f2bf(float f) {  // RNE float->bf16
  unsigned u = __float_as_uint(f);
  u += 0x7fffu + ((u >> 16) & 1u);
  return (unsigned short)(u >> 16);
}

__device__ inline float max3f(float a, float b, float c) {
  return fmaxf(fmaxf(a, b), c);  // clang fuses to v_max3_f32
}

__device__ __forceinline__ void gload_lds16(const short* g, short* l) {
  __builtin_amdgcn_global_load_lds(
      (const __attribute__((address_space(1))) void*)g,
      (__attribute__((address_space(3))) void*)l, 16, 0, 0);
}

// ---------------------------------------------------------------------------
// Block-wide sum over 256 threads (4 waves of 64)
// ---------------------------------------------------------------------------
__device__ inline float block_sum(float val) {
  __shared__ float sb[4];
  #pragma unroll
  for (int o = 32; o > 0; o >>= 1) val += __shfl_down(val, o, 64);
  int lane = threadIdx.x & 63, wid = threadIdx.x >> 6;
  if (lane == 0) sb[wid] = val;
  __syncthreads();
  float r = sb[0] + sb[1] + sb[2] + sb[3];
  __syncthreads();
  return r;
}

// ---------------------------------------------------------------------------
// LayerNorm -> bf16 output. One block per row; handles both seq1 and seq2.
// ---------------------------------------------------------------------------
__global__ __launch_bounds__(256) void ln_kernel(
    const float* __restrict__ seq1, const float* __restrict__ seq2,
    const float* __restrict__ gamma, const float* __restrict__ beta,
    short* __restrict__ x1b, short* __restrict__ x2b) {
  int row = blockIdx.x;
  const int nrows = B_ * W_;
  bool first = row < nrows;
  const float* src = first ? seq1 : seq2;
  short* dst = first ? x1b : x2b;
  int r = first ? row : row - nrows;

  const float4* p = (const float4*)(src + (size_t)r * C_);
  float4 v = p[threadIdx.x];
  float mean = block_sum(v.x + v.y + v.z + v.w) * (1.0f / C_);
  float dx = v.x - mean, dy = v.y - mean, dz = v.z - mean, dw = v.w - mean;
  float var = block_sum(dx * dx + dy * dy + dz * dz + dw * dw) * (1.0f / C_);
  float rstd = rsqrtf(var + LN_EPS);

  float4 g = ((const float4*)gamma)[threadIdx.x];
  float4 b = ((const float4*)beta)[threadIdx.x];
  uint2 o;
  o.x = (unsigned)f2bf(dx * rstd * g.x + b.x) |
        ((unsigned)f2bf(dy * rstd * g.y + b.y) << 16);
  o.y = (unsigned)f2bf(dz * rstd * g.z + b.z) |
        ((unsigned)f2bf(dw * rstd * g.w + b.w) << 16);
  ((uint2*)(dst + (size_t)r * C_))[threadIdx.x] = o;
}

// ---------------------------------------------------------------------------
// Weight prep: proj [H,C,K] fp32 -> B^T bf16 [H*K rows][C cols], q scaled by
// log2(e)/sqrt(K) (attn kernel works in exp2 domain). grid=(C/64, H, 3).
// ---------------------------------------------------------------------------
__global__ __launch_bounds__(256) void wprep_proj_kernel(
    const float* __restrict__ qp, const float* __restrict__ kp,
    const float* __restrict__ vp,
    short* __restrict__ wqt, short* __restrict__ wkt, short* __restrict__ wvt) {
  int cb = blockIdx.x, h = blockIdx.y, which = blockIdx.z;
  const float* P = (which == 0 ? qp : (which == 1 ? kp : vp)) + (size_t)h * C_ * K_;
  short* Wt = (which == 0 ? wqt : (which == 1 ? wkt : wvt));
  // q scale: 1/sqrt(64) * log2(e) so scores are in log2 units (exp2 softmax)
  float scale = (which == 0) ? 0.125f * 1.4426950408889634f : 1.0f;

  __shared__ float Ls[64][65];
  int t = threadIdx.x;
  {
    int cr = t >> 2, ks = (t & 3) * 16;
    const float* src = P + (size_t)(cb * 64 + cr) * K_ + ks;
    #pragma unroll
    for (int j = 0; j < 4; ++j) {
      float4 v = *(const float4*)(src + j * 4);
      Ls[cr][ks + j * 4 + 0] = v.x; Ls[cr][ks + j * 4 + 1] = v.y;
      Ls[cr][ks + j * 4 + 2] = v.z; Ls[cr][ks + j * 4 + 3] = v.w;
    }
  }
  __syncthreads();
  int kr = t >> 2, cs = (t & 3) * 16;
  unsigned u[8];
  #pragma unroll
  for (int i = 0; i < 8; ++i) {
    float a = Ls[cs + 2 * i][kr] * scale;
    float b = Ls[cs + 2 * i + 1][kr] * scale;
    u[i] = (unsigned)f2bf(a) | ((unsigned)f2bf(b) << 16);
  }
  short* dst = Wt + ((size_t)h * 64 + kr) * C_ + cb * 64 + cs;
  uint4 p0; p0.x = u[0]; p0.y = u[1]; p0.z = u[2]; p0.w = u[3];
  uint4 p1; p1.x = u[4]; p1.y = u[5]; p1.z = u[6]; p1.w = u[7];
  *(uint4*)dst = p0;
  *(uint4*)(dst + 8) = p1;
}

// Mixer weight: plain fp32 -> bf16 (already in B^T form: out@W.T uses W[n][c]).
__global__ __launch_bounds__(256) void wprep_mix_kernel(
    const float* __restrict__ wm, short* __restrict__ wmb) {
  int gid = blockIdx.x * 256 + threadIdx.x;
  float4 v = ((const float4*)wm)[gid];
  uint2 o;
  o.x = (unsigned)f2bf(v.x) | ((unsigned)f2bf(v.y) << 16);
  o.y = (unsigned)f2bf(v.z) | ((unsigned)f2bf(v.w) << 16);
  ((uint2*)wmb)[gid] = o;
}

// ---------------------------------------------------------------------------
// bf16 MFMA GEMM core: C[128x128] tile of A[*,1024] x Bt[*,1024]^T.
// 256 threads = 4 waves (2x2), 16x16x32 MFMA, 4x4 frags/wave, BK=64.
// global_load_lds width-16 staging; XOR-swizzled LDS (conflict-free frags).
// (round-1 exact code, non-templated)
// ---------------------------------------------------------------------------
__device__ __forceinline__ void gemm_core(
    const short* __restrict__ A, const short* __restrict__ Bt,
    int arow0, int brow0, short* As, short* Bs, float4v acc[4][4]) {
  int tid = threadIdx.x;
  int wave = tid >> 6, lane = tid & 63;
  int lr = lane >> 3, lc = lane & 7;
  int sc = lc ^ lr;                       // swizzled global chunk for staging
  int wr = wave >> 1, wc = wave & 1;
  int lg = lane >> 4, ll = lane & 15;

  #pragma unroll
  for (int mi = 0; mi < 4; ++mi)
    #pragma unroll
    for (int ni = 0; ni < 4; ++ni) {
      acc[mi][ni][0] = 0.f; acc[mi][ni][1] = 0.f;
      acc[mi][ni][2] = 0.f; acc[mi][ni][3] = 0.f;
    }

  for (int k0 = 0; k0 < C_; k0 += 64) {
    __syncthreads();
    #pragma unroll
    for (int j = 0; j < 4; ++j) {
      int seg = wave * 4 + j;            // 8-row segment of the 128-row tile
      int r = seg * 8 + lr;
      gload_lds16(A + (size_t)(arow0 + r) * C_ + k0 + sc * 8, As + seg * 512);
      gload_lds16(Bt + (size_t)(brow0 + r) * C_ + k0 + sc * 8, Bs + seg * 512);
    }
    __syncthreads();
    #pragma unroll
    for (int kc = 0; kc < 2; ++kc) {
      int cc = kc * 4 + lg;
      short8 af[4], bf[4];
      #pragma unroll
      for (int mi = 0; mi < 4; ++mi) {
        int m = wr * 64 + mi * 16 + ll;
        af[mi] = *(const short8*)&As[m * 64 + ((cc ^ (m & 7)) << 3)];
      }
      #pragma unroll
      for (int ni = 0; ni < 4; ++ni) {
        int n = wc * 64 + ni * 16 + ll;
        bf[ni] = *(const short8*)&Bs[n * 64 + ((cc ^ (n & 7)) << 3)];
      }
      #pragma unroll
      for (int mi = 0; mi < 4; ++mi)
        #pragma unroll
        for (int ni = 0; ni < 4; ++ni)
          acc[mi][ni] = __builtin_amdgcn_mfma_f32_16x16x32_bf16(
              af[mi], bf[ni], acc[mi][ni], 0, 0, 0);
    }
  }
}

// ---------------------------------------------------------------------------
// 64-row variant for the mixer: C[64x128] tile. (round-4 proven)
// A: 64 rows = 8 segs (2 per wave); B: 128 rows = 16 segs. 2x4 frags/wave.
// ---------------------------------------------------------------------------
__device__ __forceinline__ void gemm_core64(
    const short* __restrict__ A, const short* __restrict__ Bt,
    int arow0, int brow0, short* As, short* Bs, float4v acc[2][4]) {
  int tid = threadIdx.x;
  int wave = tid >> 6, lane = tid & 63;
  int lr = lane >> 3, lc = lane & 7;
  int sc = lc ^ lr;                       // swizzled global chunk for staging
  int wr = wave >> 1, wc = wave & 1;
  int lg = lane >> 4, ll = lane & 15;

  #pragma unroll
  for (int mi = 0; mi < 2; ++mi)
    #pragma unroll
    for (int ni = 0; ni < 4; ++ni) {
      acc[mi][ni][0] = 0.f; acc[mi][ni][1] = 0.f;
      acc[mi][ni][2] = 0.f; acc[mi][ni][3] = 0.f;
    }

  for (int k0 = 0; k0 < C_; k0 += 64) {
    __syncthreads();
    #pragma unroll
    for (int j = 0; j < 2; ++j) {        // A: 64 rows = 8 segs of 8
      int seg = wave * 2 + j;
      int r = seg * 8 + lr;
      gload_lds16(A + (size_t)(arow0 + r) * C_ + k0 + sc * 8, As + seg * 512);
    }
    #pragma unroll
    for (int j = 0; j < 4; ++j) {        // B: 128 rows = 16 segs
      int seg = wave * 4 + j;
      int r = seg * 8 + lr;
      gload_lds16(Bt + (size_t)(brow0 + r) * C_ + k0 + sc * 8, Bs + seg * 512);
    }
    __syncthreads();
    #pragma unroll
    for (int kc = 0; kc < 2; ++kc) {
      int cc = kc * 4 + lg;
      short8 af[2], bf[4];
      #pragma unroll
      for (int mi = 0; mi < 2; ++mi) {
        int m = wr * 32 + mi * 16 + ll;
        af[mi] = *(const short8*)&As[m * 64 + ((cc ^ (m & 7)) << 3)];
      }
      #pragma unroll
      for (int ni = 0; ni < 4; ++ni) {
        int n = wc * 64 + ni * 16 + ll;
        bf[ni] = *(const short8*)&Bs[n * 64 + ((cc ^ (n & 7)) << 3)];
      }
      #pragma unroll
      for (int mi = 0; mi < 2; ++mi)
        #pragma unroll
        for (int ni = 0; ni < 4; ++ni)
          acc[mi][ni] = __builtin_amdgcn_mfma_f32_16x16x32_bf16(
              af[mi], bf[ni], acc[mi][ni], 0, 0, 0);
    }
  }
}

// ---------------------------------------------------------------------------
// QKV GEMMs, fused in grid.z: z=0 Q=x1@Wq^T, z=1 K=x2@Wk^T,
// z=2 V^T = Wv x2^T (operand-swapped so stores into [B,H,K,W] coalesce).
// Outputs bf16. grid=(32,8,3).  (round-4 byte-identical)
// ---------------------------------------------------------------------------
__global__ __launch_bounds__(256, 3) void gemm_qkv_kernel(
    const short* __restrict__ x1b, const short* __restrict__ x2b,
    const short* __restrict__ wqt, const short* __restrict__ wkt,
    const short* __restrict__ wvt,
    short* __restrict__ qb, short* __restrict__ kb, short* __restrict__ vtb) {
  __shared__ short As[128 * 64], Bs[128 * 64];
  int z = blockIdx.z;
  const short *A, *Bt;
  int arow0, brow0;
  if (z == 0)      { A = x1b; Bt = wqt; arow0 = blockIdx.x * 128; brow0 = blockIdx.y * 128; }
  else if (z == 1) { A = x2b; Bt = wkt; arow0 = blockIdx.x * 128; brow0 = blockIdx.y * 128; }
  else             { A = wvt; Bt = x2b; arow0 = blockIdx.y * 128; brow0 = blockIdx.x * 128; }

  float4v acc[4][4];
  gemm_core(A, Bt, arow0, brow0, As, Bs, acc);

  int wave = threadIdx.x >> 6, lane = threadIdx.x & 63;
  int wr = wave >> 1, wc = wave & 1, lg = lane >> 4, ll = lane & 15;
  if (z <= 1) {
    short* O = (z == 0) ? qb : kb;
    #pragma unroll
    for (int mi = 0; mi < 4; ++mi)
      #pragma unroll
      for (int ni = 0; ni < 4; ++ni) {
        int n = brow0 + wc * 64 + ni * 16 + ll;       // h*64+k
        int h = n >> 6, kk = n & 63;
        #pragma unroll
        for (int r2 = 0; r2 < 4; ++r2) {
          int m = arow0 + wr * 64 + mi * 16 + lg * 4 + r2;  // seq index
          int b = m >> 11, w = m & (W_ - 1);
          O[((size_t)(b * H_ + h) * W_ + w) * K_ + kk] = (short)f2bf(acc[mi][ni][r2]);
        }
      }
  } else {
    #pragma unroll
    for (int mi = 0; mi < 4; ++mi)
      #pragma unroll
      for (int ni = 0; ni < 4; ++ni) {
        int n = brow0 + wc * 64 + ni * 16 + ll;       // seq index
        int b = n >> 11, w = n & (W_ - 1);
        #pragma unroll
        for (int r2 = 0; r2 < 4; ++r2) {
          int m = arow0 + wr * 64 + mi * 16 + lg * 4 + r2;  // h*64+k
          int h = m >> 6, kk = m & 63;
          vtb[((size_t)(b * H_ + h) * K_ + kk) * W_ + w] = (short)f2bf(acc[mi][ni][r2]);
        }
      }
  }
}

// ---------------------------------------------------------------------------
// Mixer GEMM: out[4096,1024] fp32 = attnb @ wmb^T + bias. grid=(64,8)=512
// blocks = 2/CU. (round-4 proven)
// ---------------------------------------------------------------------------
__global__ __launch_bounds__(256, 3) void gemm_mix_kernel(
    const short* __restrict__ attnb, const short* __restrict__ wmb,
    const float* __restrict__ bias, float* __restrict__ out) {
  __shared__ short As[64 * 64], Bs[128 * 64];
  int arow0 = blockIdx.x * 64, brow0 = blockIdx.y * 128;
  float4v acc[2][4];
  gemm_core64(attnb, wmb, arow0, brow0, As, Bs, acc);

  int wave = threadIdx.x >> 6, lane = threadIdx.x & 63;
  int wr = wave >> 1, wc = wave & 1, lg = lane >> 4, ll = lane & 15;
  #pragma unroll
  for (int mi = 0; mi < 2; ++mi)
    #pragma unroll
    for (int ni = 0; ni < 4; ++ni) {
      int n = brow0 + wc * 64 + ni * 16 + ll;
      float bv = bias[n];
      #pragma unroll
      for (int r2 = 0; r2 < 4; ++r2) {
        int m = arow0 + wr * 32 + mi * 16 + lg * 4 + r2;
        out[(size_t)m * C_ + n] = acc[mi][ni][r2] + bv;
      }
    }
}

// ---------------------------------------------------------------------------
// Causal flash attention — round-6 proven kernel widened to a 128-row Q-tile.
// Each wave owns TWO 16-row q-sets (A: qt*128+w*16+ll, B: +64) sharing every
// K/V tile: bk/bv LDS reads, staging, vmcnt waits and barriers amortize over
// 2x the MFMA work (36/iter vs 18). nkt = 2qt+2; half A skips only the final
// key tile (its rows see no keys there); mask expressions are index-identical
// per half (key_in_tile > wave*16+ll on each half's diagonal tile).
// grid=(32,16)=512 blocks = exactly 2/CU (all resident); slot map
// qt = s<8 ? 15-s : s-8 pairs heavy+light per CU (~34 unit-iters each).
// Ps reused sequentially between halves (DS ops are in-order per wave -> WAR
// safe). __launch_bounds__(256,2) caps VGPR at 256: no spill, so the
// hand-counted vmcnt(4) stays sound (round-2 lesson).
// ---------------------------------------------------------------------------
__global__ __launch_bounds__(256, 2) void attn_mfma_kernel(
    const short* __restrict__ q, const short* __restrict__ k,
    const short* __restrict__ vt, short* __restrict__ out) {
  int bh = blockIdx.x;                    // 0..31
  int b = bh >> 4, h = bh & 15;
  int s = blockIdx.y;                     // 0..15
  int qt = (s < 8) ? (15 - s) : (s - 8);  // balanced heavy/light pairing
  int wave = threadIdx.x >> 6;
  int lane = threadIdx.x & 63;
  int lg = lane >> 4, ll = lane & 15;

  __shared__ short Ks[2][64 * 64];        // [key][chan], swizzled chunks
  __shared__ short Vs[2][64 * 64];        // [chan][key], swizzled chunks
  __shared__ short Ps[4][16 * 72];        // per-wave P buffer (halves reuse)

  const short* qp = q + (size_t)bh * W_ * K_;
  const short* kp = k + (size_t)bh * W_ * K_;
  const short* vb = vt + (size_t)bh * K_ * W_;

  int qrowA = qt * 128 + wave * 16 + ll;
  int qrowB = qrowA + 64;
  short8 aqA[2], aqB[2];
  #pragma unroll
  for (int kc = 0; kc < 2; ++kc) {
    aqA[kc] = *(const short8*)(qp + (size_t)qrowA * K_ + kc * 32 + lg * 8);
    aqB[kc] = *(const short8*)(qp + (size_t)qrowB * K_ + kc * 32 + lg * 8);
  }

  short8 ones;                            // bf16 1.0 x8, A-frag for l-sum MFMA
  #pragma unroll
  for (int i = 0; i < 8; ++i) ones[i] = (short)0x3F80;

  float4v oA[4], oB[4];
  #pragma unroll
  for (int ct = 0; ct < 4; ++ct) {
    oA[ct][0] = 0.f; oA[ct][1] = 0.f; oA[ct][2] = 0.f; oA[ct][3] = 0.f;
    oB[ct][0] = 0.f; oB[ct][1] = 0.f; oB[ct][2] = 0.f; oB[ct][3] = 0.f;
  }
  float4v lsA, lsB;
  lsA[0] = 0.f; lsA[1] = 0.f; lsA[2] = 0.f; lsA[3] = 0.f;
  lsB[0] = 0.f; lsB[1] = 0.f; lsB[2] = 0.f; lsB[3] = 0.f;
  float mA = -INFINITY, mB = -INFINITY;

  int nkt = 2 * qt + 2;

  #define STAGE(kt, buf)                                                   \
    {                                                                      \
      const short* kbase = kp + (size_t)(kt) * 64 * K_;                    \
      const short* vbase = vb + (kt) * 64;                                 \
      _Pragma("unroll")                                                    \
      for (int j = 0; j < 2; ++j) {                                        \
        int sdx = j * 256 + (int)threadIdx.x;                              \
        int mm = sdx >> 3, c7 = sdx & 7;                                   \
        int gc = c7 ^ (mm & 7);                                            \
        gload_lds16(kbase + (size_t)mm * K_ + gc * 8, &Ks[buf][sdx * 8]);  \
        gload_lds16(vbase + (size_t)mm * W_ + gc * 8, &Vs[buf][sdx * 8]);  \
      }                                                                    \
    }

  STAGE(0, 0);
  for (int kt = 0; kt < nkt; ++kt) {
    int cur = kt & 1;
    if (kt + 1 < nkt) {
      STAGE(kt + 1, cur ^ 1);
      // wait only the current buffer's 4 loads; prefetch stays in flight
      asm volatile("s_waitcnt vmcnt(4)\ns_barrier" ::: "memory");
    } else {
      asm volatile("s_waitcnt vmcnt(0)\ns_barrier" ::: "memory");
    }

    bool haveA = (kt <= 2 * qt);          // block-uniform

    // ---- S^T = K.Q^T for both halves, sharing bk frags ----
    float4v stA[4], stB[4];
    __builtin_amdgcn_s_setprio(1);
    if (haveA) {
      #pragma unroll
      for (int nt = 0; nt < 4; ++nt) {
        stA[nt][0] = 0.f; stA[nt][1] = 0.f; stA[nt][2] = 0.f; stA[nt][3] = 0.f;
        stB[nt][0] = 0.f; stB[nt][1] = 0.f; stB[nt][2] = 0.f; stB[nt][3] = 0.f;
        int n = nt * 16 + ll;
        #pragma unroll
        for (int kc = 0; kc < 2; ++kc) {
          int cc = kc * 4 + lg;
          short8 bk = *(const short8*)&Ks[cur][n * 64 + ((cc ^ (n & 7)) << 3)];
          stA[nt] = __builtin_amdgcn_mfma_f32_16x16x32_bf16(bk, aqA[kc], stA[nt], 0, 0, 0);
          stB[nt] = __builtin_amdgcn_mfma_f32_16x16x32_bf16(bk, aqB[kc], stB[nt], 0, 0, 0);
        }
      }
    } else {
      #pragma unroll
      for (int nt = 0; nt < 4; ++nt) {
        stB[nt][0] = 0.f; stB[nt][1] = 0.f; stB[nt][2] = 0.f; stB[nt][3] = 0.f;
        int n = nt * 16 + ll;
        #pragma unroll
        for (int kc = 0; kc < 2; ++kc) {
          int cc = kc * 4 + lg;
          short8 bk = *(const short8*)&Ks[cur][n * 64 + ((cc ^ (n & 7)) << 3)];
          stB[nt] = __builtin_amdgcn_mfma_f32_16x16x32_bf16(bk, aqB[kc], stB[nt], 0, 0, 0);
        }
      }
    }
    __builtin_amdgcn_s_setprio(0);

    // ---- V^T frags (A operand of PV), shared by both halves ----
    short8 bv[4][2];
    #pragma unroll
    for (int ct = 0; ct < 4; ++ct) {
      int c = ct * 16 + ll;
      #pragma unroll
      for (int kc = 0; kc < 2; ++kc) {
        int cc = kc * 4 + lg;
        bv[ct][kc] = *(const short8*)&Vs[cur][c * 64 + ((cc ^ (c & 7)) << 3)];
      }
    }

    // ---- causal masks (diagonal tiles) ----
    if (kt == 2 * qt) {                   // half A diagonal
      #pragma unroll
      for (int nt = 0; nt < 4; ++nt) {
        int keyb = nt * 16 + lg * 4;
        #pragma unroll
        for (int r = 0; r < 4; ++r)
          if (keyb + r > wave * 16 + ll) stA[nt][r] = -INFINITY;
      }
    }
    if (kt == 2 * qt + 1) {               // half B diagonal (last iter)
      #pragma unroll
      for (int nt = 0; nt < 4; ++nt) {
        int keyb = nt * 16 + lg * 4;
        #pragma unroll
        for (int r = 0; r < 4; ++r)
          if (keyb + r > wave * 16 + ll) stB[nt][r] = -INFINITY;
      }
    }

    short* myP = &Ps[wave][ll * 72];

    // ================= half A: softmax + P + PV =================
    if (haveA) {
      float ma = max3f(stA[0][0], stA[0][1], stA[0][2]);
      float mb2 = max3f(stA[0][3], stA[1][0], stA[1][1]);
      float mc = max3f(stA[1][2], stA[1][3], stA[2][0]);
      float md = max3f(stA[2][1], stA[2][2], stA[2][3]);
      float me = max3f(stA[3][0], stA[3][1], stA[3][2]);
      float lm = fmaxf(max3f(ma, mb2, mc), max3f(md, me, stA[3][3]));
      lm = fmaxf(lm, __shfl_xor(lm, 16, 64));
      lm = fmaxf(lm, __shfl_xor(lm, 32, 64));
      if (!__all(lm <= mA + 8.f)) {
        float nm = fmaxf(mA, lm);
        float al = EXP2(mA - nm);
        mA = nm;
        lsA[0] *= al; lsA[1] *= al; lsA[2] *= al; lsA[3] *= al;
        #pragma unroll
        for (int ct = 0; ct < 4; ++ct) {
          oA[ct][0] *= al; oA[ct][1] *= al; oA[ct][2] *= al; oA[ct][3] *= al;
        }
      }
      float p[4][4];
      #pragma unroll
      for (int nt = 0; nt < 4; ++nt)
        #pragma unroll
        for (int r = 0; r < 4; ++r)
          p[nt][r] = EXP2(stA[nt][r] - mA);
      #pragma unroll
      for (int nt = 0; nt < 4; ++nt) {
        uint2 w;
        w.x = (unsigned)f2bf(p[nt][0]) | ((unsigned)f2bf(p[nt][1]) << 16);
        w.y = (unsigned)f2bf(p[nt][2]) | ((unsigned)f2bf(p[nt][3]) << 16);
        *(uint2*)(myP + nt * 16 + lg * 4) = w;
      }
      __builtin_amdgcn_s_waitcnt(0xC07F);  // lgkmcnt(0), wave-private
      short8 bp0 = *(const short8*)(myP + lg * 8);
      short8 bp1 = *(const short8*)(myP + 32 + lg * 8);
      __builtin_amdgcn_s_setprio(1);
      lsA = __builtin_amdgcn_mfma_f32_16x16x32_bf16(ones, bp0, lsA, 0, 0, 0);
      lsA = __builtin_amdgcn_mfma_f32_16x16x32_bf16(ones, bp1, lsA, 0, 0, 0);
      #pragma unroll
      for (int ct = 0; ct < 4; ++ct) {
        oA[ct] = __builtin_amdgcn_mfma_f32_16x16x32_bf16(bv[ct][0], bp0, oA[ct], 0, 0, 0);
        oA[ct] = __builtin_amdgcn_mfma_f32_16x16x32_bf16(bv[ct][1], bp1, oA[ct], 0, 0, 0);
      }
      __builtin_amdgcn_s_setprio(0);
    }

    // ================= half B: softmax + P + PV =================
    {
      float ma = max3f(stB[0][0], stB[0][1], stB[0][2]);
      float mb2 = max3f(stB[0][3], stB[1][0], stB[1][1]);
      float mc = max3f(stB[1][2], stB[1][3], stB[2][0]);
      float md = max3f(stB[2][1], stB[2][2], stB[2][3]);
      float me = max3f(stB[3][0], stB[3][1], stB[3][2]);
      float lm = fmaxf(max3f(ma, mb2, mc), max3f(md, me, stB[3][3]));
      lm = fmaxf(lm, __shfl_xor(lm, 16, 64));
      lm = fmaxf(lm, __shfl_xor(lm, 32, 64));
      if (!__all(lm <= mB + 8.f)) {
        float nm = fmaxf(mB, lm);
        float al = EXP2(mB - nm);
        mB = nm;
        lsB[0] *= al; lsB[1] *= al; lsB[2] *= al; lsB[3] *= al;
        #pragma unroll
        for (int ct = 0; ct < 4; ++ct) {
          oB[ct][0] *= al; oB[ct][1] *= al; oB[ct][2] *= al; oB[ct][3] *= al;
        }
      }
      float p[4][4];
      #pragma unroll
      for (int nt = 0; nt < 4; ++nt)
        #pragma unroll
        for (int r = 0; r < 4; ++r)
          p[nt][r] = EXP2(stB[nt][r] - mB);
      #pragma unroll
      for (int nt = 0; nt < 4; ++nt) {
        uint2 w;
        w.x = (unsigned)f2bf(p[nt][0]) | ((unsigned)f2bf(p[nt][1]) << 16);
        w.y = (unsigned)f2bf(p[nt][2]) | ((unsigned)f2bf(p[nt][3]) << 16);
        *(uint2*)(myP + nt * 16 + lg * 4) = w;   // WAR on half A reads: DS in-order per wave
      }
      __builtin_amdgcn_s_waitcnt(0xC07F);  // lgkmcnt(0), wave-private
      short8 bp0 = *(const short8*)(myP + lg * 8);
      short8 bp1 = *(const short8*)(myP + 32 + lg * 8);
      __builtin_amdgcn_s_setprio(1);
      lsB = __builtin_amdgcn_mfma_f32_16x16x32_bf16(ones, bp0, lsB, 0, 0, 0);
      lsB = __builtin_amdgcn_mfma_f32_16x16x32_bf16(ones, bp1, lsB, 0, 0, 0);
      #pragma unroll
      for (int ct = 0; ct < 4; ++ct) {
        oB[ct] = __builtin_amdgcn_mfma_f32_16x16x32_bf16(bv[ct][0], bp0, oB[ct], 0, 0, 0);
        oB[ct] = __builtin_amdgcn_mfma_f32_16x16x32_bf16(bv[ct][1], bp1, oB[ct], 0, 0, 0);
      }
      __builtin_amdgcn_s_setprio(0);
    }

    // release current buffer for the next-next stage; do NOT drain vmem
    asm volatile("s_waitcnt lgkmcnt(0)\ns_barrier" ::: "memory");
  }
  #undef STAGE

  // ---- epilogue: normalize (lane-local), write bf16 [B,W,C] as 8B packs ----
  {
    float invl = 1.0f / lsA[0];
    size_t orow = ((size_t)(b * W_ + qrowA)) * C_ + h * K_;
    #pragma unroll
    for (int ct = 0; ct < 4; ++ct) {
      uint2 w;
      w.x = (unsigned)f2bf(oA[ct][0] * invl) | ((unsigned)f2bf(oA[ct][1] * invl) << 16);
      w.y = (unsigned)f2bf(oA[ct][2] * invl) | ((unsigned)f2bf(oA[ct][3] * invl) << 16);
      *(uint2*)(out + orow + ct * 16 + lg * 4) = w;
    }
  }
  {
    float invl = 1.0f / lsB[0];
    size_t orow = ((size_t)(b * W_ + qrowB)) * C_ + h * K_;
    #pragma unroll
    for (int ct = 0; ct < 4; ++ct) {
      uint2 w;
      w.x = (unsigned)f2bf(oB[ct][0] * invl) | ((unsigned)f2bf(oB[ct][1] * invl) << 16);
      w.y = (unsigned)f2bf(oB[ct][2] * invl) | ((unsigned)f2bf(oB[ct][3] * invl) << 16);
      *(uint2*)(out + orow + ct * 16 + lg * 4) = w;
    }
  }
}

// ---------------------------------------------------------------------------
extern "C" void kernel_launch(void* const* d_in, const int* in_sizes, int n_in,
                              void* d_out, int out_size, void* d_ws, size_t ws_size,
                              hipStream_t stream) {
  const float* seq1  = (const float*)d_in[0];
  const float* seq2  = (const float*)d_in[1];
  const float* gamma = (const float*)d_in[2];
  const float* beta  = (const float*)d_in[3];
  const float* qp    = (const float*)d_in[4];
  const float* kp    = (const float*)d_in[5];
  const float* vp    = (const float*)d_in[6];
  const float* wm    = (const float*)d_in[7];
  const float* mb    = (const float*)d_in[8];
  float* out = (float*)d_out;

  char* ws = (char*)d_ws;
  const size_t NROW = (size_t)B_ * W_;               // 4096
  const size_t XB = NROW * C_ * sizeof(short);       // 8 MB bf16 activation buf
  const size_t WB = (size_t)C_ * C_ * sizeof(short); // 2 MB bf16 weight buf
  short* x1b = (short*)(ws);
  short* x2b = (short*)(ws + XB);
  short* qb  = (short*)(ws + 2 * XB);
  short* kb  = (short*)(ws + 3 * XB);
  short* vtb = (short*)(ws + 4 * XB);
  short* wqt = (short*)(ws + 5 * XB);
  short* wkt = (short*)(ws + 5 * XB + WB);
  short* wvt = (short*)(ws + 5 * XB + 2 * WB);
  short* wmb = (short*)(ws + 5 * XB + 3 * WB);
  short* attnb = (short*)(ws + 5 * XB + 4 * WB);

  wprep_proj_kernel<<<dim3(C_ / 64, H_, 3), dim3(256), 0, stream>>>(
      qp, kp, vp, wqt, wkt, wvt);
  wprep_mix_kernel<<<dim3(C_ * C_ / 1024), dim3(256), 0, stream>>>(wm, wmb);
  ln_kernel<<<dim3(2 * (unsigned)NROW), dim3(256), 0, stream>>>(
      seq1, seq2, gamma, beta, x1b, x2b);
  gemm_qkv_kernel<<<dim3(32, 8, 3), dim3(256), 0, stream>>>(
      x1b, x2b, wqt, wkt, wvt, qb, kb, vtb);
  attn_mfma_kernel<<<dim3(32, 16), dim3(256), 0, stream>>>(
      qb, kb, vtb, attnb);
  gemm_mix_kernel<<<dim3(64, 8), dim3(256), 0, stream>>>(attnb, wmb, mb, out);
}

// Round 8
// 188.707 us; speedup vs baseline: 1.1609x; 1.1609x over previous
//
#include <hip/hip_runtime.h>
#include <math.h>

#define B_ 2
#define W_ 2048
#define C_ 1024
#define H_ 16
#define K_ 64
#define LN_EPS 1e-5f

typedef __attribute__((ext_vector_type(8))) short short8;   // 8 bf16 (4 VGPRs)
typedef __attribute__((ext_vector_type(4))) float float4v;  // MFMA C/D frag

#if __has_builtin(__builtin_amdgcn_exp2f)
#define EXP2(x) __builtin_amdgcn_exp2f(x)
#else
#define EXP2(x) exp2f(x)
#endif

__device__ inline unsigned short f2bf(float f) {  // RNE float->bf16
  unsigned u = __float_as_uint(f);
  u += 0x7fffu + ((u >> 16) & 1u);
  return (unsigned short)(u >> 16);
}

__device__ inline float max3f(float a, float b, float c) {
  return fmaxf(fmaxf(a, b), c);  // clang fuses to v_max3_f32
}

__device__ __forceinline__ void gload_lds16(const short* g, short* l) {
  __builtin_amdgcn_global_load_lds(
      (const __attribute__((address_space(1))) void*)g,
      (__attribute__((address_space(3))) void*)l, 16, 0, 0);
}

// ---------------------------------------------------------------------------
// Block-wide sum over 256 threads (4 waves of 64)
// ---------------------------------------------------------------------------
__device__ inline float block_sum(float val) {
  __shared__ float sb[4];
  #pragma unroll
  for (int o = 32; o > 0; o >>= 1) val += __shfl_down(val, o, 64);
  int lane = threadIdx.x & 63, wid = threadIdx.x >> 6;
  if (lane == 0) sb[wid] = val;
  __syncthreads();
  float r = sb[0] + sb[1] + sb[2] + sb[3];
  __syncthreads();
  return r;
}

// ---------------------------------------------------------------------------
// LayerNorm -> bf16 output. One block per row; handles both seq1 and seq2.
// ---------------------------------------------------------------------------
__global__ __launch_bounds__(256) void ln_kernel(
    const float* __restrict__ seq1, const float* __restrict__ seq2,
    const float* __restrict__ gamma, const float* __restrict__ beta,
    short* __restrict__ x1b, short* __restrict__ x2b) {
  int row = blockIdx.x;
  const int nrows = B_ * W_;
  bool first = row < nrows;
  const float* src = first ? seq1 : seq2;
  short* dst = first ? x1b : x2b;
  int r = first ? row : row - nrows;

  const float4* p = (const float4*)(src + (size_t)r * C_);
  float4 v = p[threadIdx.x];
  float mean = block_sum(v.x + v.y + v.z + v.w) * (1.0f / C_);
  float dx = v.x - mean, dy = v.y - mean, dz = v.z - mean, dw = v.w - mean;
  float var = block_sum(dx * dx + dy * dy + dz * dz + dw * dw) * (1.0f / C_);
  float rstd = rsqrtf(var + LN_EPS);

  float4 g = ((const float4*)gamma)[threadIdx.x];
  float4 b = ((const float4*)beta)[threadIdx.x];
  uint2 o;
  o.x = (unsigned)f2bf(dx * rstd * g.x + b.x) |
        ((unsigned)f2bf(dy * rstd * g.y + b.y) << 16);
  o.y = (unsigned)f2bf(dz * rstd * g.z + b.z) |
        ((unsigned)f2bf(dw * rstd * g.w + b.w) << 16);
  ((uint2*)(dst + (size_t)r * C_))[threadIdx.x] = o;
}

// ---------------------------------------------------------------------------
// Weight prep: proj [H,C,K] fp32 -> B^T bf16 [H*K rows][C cols], q scaled by
// log2(e)/sqrt(K) (attn kernel works in exp2 domain). grid=(C/64, H, 3).
// ---------------------------------------------------------------------------
__global__ __launch_bounds__(256) void wprep_proj_kernel(
    const float* __restrict__ qp, const float* __restrict__ kp,
    const float* __restrict__ vp,
    short* __restrict__ wqt, short* __restrict__ wkt, short* __restrict__ wvt) {
  int cb = blockIdx.x, h = blockIdx.y, which = blockIdx.z;
  const float* P = (which == 0 ? qp : (which == 1 ? kp : vp)) + (size_t)h * C_ * K_;
  short* Wt = (which == 0 ? wqt : (which == 1 ? wkt : wvt));
  // q scale: 1/sqrt(64) * log2(e) so scores are in log2 units (exp2 softmax)
  float scale = (which == 0) ? 0.125f * 1.4426950408889634f : 1.0f;

  __shared__ float Ls[64][65];
  int t = threadIdx.x;
  {
    int cr = t >> 2, ks = (t & 3) * 16;
    const float* src = P + (size_t)(cb * 64 + cr) * K_ + ks;
    #pragma unroll
    for (int j = 0; j < 4; ++j) {
      float4 v = *(const float4*)(src + j * 4);
      Ls[cr][ks + j * 4 + 0] = v.x; Ls[cr][ks + j * 4 + 1] = v.y;
      Ls[cr][ks + j * 4 + 2] = v.z; Ls[cr][ks + j * 4 + 3] = v.w;
    }
  }
  __syncthreads();
  int kr = t >> 2, cs = (t & 3) * 16;
  unsigned u[8];
  #pragma unroll
  for (int i = 0; i < 8; ++i) {
    float a = Ls[cs + 2 * i][kr] * scale;
    float b = Ls[cs + 2 * i + 1][kr] * scale;
    u[i] = (unsigned)f2bf(a) | ((unsigned)f2bf(b) << 16);
  }
  short* dst = Wt + ((size_t)h * 64 + kr) * C_ + cb * 64 + cs;
  uint4 p0; p0.x = u[0]; p0.y = u[1]; p0.z = u[2]; p0.w = u[3];
  uint4 p1; p1.x = u[4]; p1.y = u[5]; p1.z = u[6]; p1.w = u[7];
  *(uint4*)dst = p0;
  *(uint4*)(dst + 8) = p1;
}

// Mixer weight: plain fp32 -> bf16 (already in B^T form: out@W.T uses W[n][c]).
__global__ __launch_bounds__(256) void wprep_mix_kernel(
    const float* __restrict__ wm, short* __restrict__ wmb) {
  int gid = blockIdx.x * 256 + threadIdx.x;
  float4 v = ((const float4*)wm)[gid];
  uint2 o;
  o.x = (unsigned)f2bf(v.x) | ((unsigned)f2bf(v.y) << 16);
  o.y = (unsigned)f2bf(v.z) | ((unsigned)f2bf(v.w) << 16);
  ((uint2*)wmb)[gid] = o;
}

// ---------------------------------------------------------------------------
// bf16 MFMA GEMM core: C[128x128] tile of A[*,1024] x Bt[*,1024]^T.
// 256 threads = 4 waves (2x2), 16x16x32 MFMA, 4x4 frags/wave, BK=64.
// global_load_lds width-16 staging; XOR-swizzled LDS (conflict-free frags).
// (round-1 exact code, non-templated)
// ---------------------------------------------------------------------------
__device__ __forceinline__ void gemm_core(
    const short* __restrict__ A, const short* __restrict__ Bt,
    int arow0, int brow0, short* As, short* Bs, float4v acc[4][4]) {
  int tid = threadIdx.x;
  int wave = tid >> 6, lane = tid & 63;
  int lr = lane >> 3, lc = lane & 7;
  int sc = lc ^ lr;                       // swizzled global chunk for staging
  int wr = wave >> 1, wc = wave & 1;
  int lg = lane >> 4, ll = lane & 15;

  #pragma unroll
  for (int mi = 0; mi < 4; ++mi)
    #pragma unroll
    for (int ni = 0; ni < 4; ++ni) {
      acc[mi][ni][0] = 0.f; acc[mi][ni][1] = 0.f;
      acc[mi][ni][2] = 0.f; acc[mi][ni][3] = 0.f;
    }

  for (int k0 = 0; k0 < C_; k0 += 64) {
    __syncthreads();
    #pragma unroll
    for (int j = 0; j < 4; ++j) {
      int seg = wave * 4 + j;            // 8-row segment of the 128-row tile
      int r = seg * 8 + lr;
      gload_lds16(A + (size_t)(arow0 + r) * C_ + k0 + sc * 8, As + seg * 512);
      gload_lds16(Bt + (size_t)(brow0 + r) * C_ + k0 + sc * 8, Bs + seg * 512);
    }
    __syncthreads();
    #pragma unroll
    for (int kc = 0; kc < 2; ++kc) {
      int cc = kc * 4 + lg;
      short8 af[4], bf[4];
      #pragma unroll
      for (int mi = 0; mi < 4; ++mi) {
        int m = wr * 64 + mi * 16 + ll;
        af[mi] = *(const short8*)&As[m * 64 + ((cc ^ (m & 7)) << 3)];
      }
      #pragma unroll
      for (int ni = 0; ni < 4; ++ni) {
        int n = wc * 64 + ni * 16 + ll;
        bf[ni] = *(const short8*)&Bs[n * 64 + ((cc ^ (n & 7)) << 3)];
      }
      #pragma unroll
      for (int mi = 0; mi < 4; ++mi)
        #pragma unroll
        for (int ni = 0; ni < 4; ++ni)
          acc[mi][ni] = __builtin_amdgcn_mfma_f32_16x16x32_bf16(
              af[mi], bf[ni], acc[mi][ni], 0, 0, 0);
    }
  }
}

// ---------------------------------------------------------------------------
// 64-row variant for the mixer: C[64x128] tile. (round-4 proven)
// A: 64 rows = 8 segs (2 per wave); B: 128 rows = 16 segs. 2x4 frags/wave.
// ---------------------------------------------------------------------------
__device__ __forceinline__ void gemm_core64(
    const short* __restrict__ A, const short* __restrict__ Bt,
    int arow0, int brow0, short* As, short* Bs, float4v acc[2][4]) {
  int tid = threadIdx.x;
  int wave = tid >> 6, lane = tid & 63;
  int lr = lane >> 3, lc = lane & 7;
  int sc = lc ^ lr;                       // swizzled global chunk for staging
  int wr = wave >> 1, wc = wave & 1;
  int lg = lane >> 4, ll = lane & 15;

  #pragma unroll
  for (int mi = 0; mi < 2; ++mi)
    #pragma unroll
    for (int ni = 0; ni < 4; ++ni) {
      acc[mi][ni][0] = 0.f; acc[mi][ni][1] = 0.f;
      acc[mi][ni][2] = 0.f; acc[mi][ni][3] = 0.f;
    }

  for (int k0 = 0; k0 < C_; k0 += 64) {
    __syncthreads();
    #pragma unroll
    for (int j = 0; j < 2; ++j) {        // A: 64 rows = 8 segs of 8
      int seg = wave * 2 + j;
      int r = seg * 8 + lr;
      gload_lds16(A + (size_t)(arow0 + r) * C_ + k0 + sc * 8, As + seg * 512);
    }
    #pragma unroll
    for (int j = 0; j < 4; ++j) {        // B: 128 rows = 16 segs
      int seg = wave * 4 + j;
      int r = seg * 8 + lr;
      gload_lds16(Bt + (size_t)(brow0 + r) * C_ + k0 + sc * 8, Bs + seg * 512);
    }
    __syncthreads();
    #pragma unroll
    for (int kc = 0; kc < 2; ++kc) {
      int cc = kc * 4 + lg;
      short8 af[2], bf[4];
      #pragma unroll
      for (int mi = 0; mi < 2; ++mi) {
        int m = wr * 32 + mi * 16 + ll;
        af[mi] = *(const short8*)&As[m * 64 + ((cc ^ (m & 7)) << 3)];
      }
      #pragma unroll
      for (int ni = 0; ni < 4; ++ni) {
        int n = wc * 64 + ni * 16 + ll;
        bf[ni] = *(const short8*)&Bs[n * 64 + ((cc ^ (n & 7)) << 3)];
      }
      #pragma unroll
      for (int mi = 0; mi < 2; ++mi)
        #pragma unroll
        for (int ni = 0; ni < 4; ++ni)
          acc[mi][ni] = __builtin_amdgcn_mfma_f32_16x16x32_bf16(
              af[mi], bf[ni], acc[mi][ni], 0, 0, 0);
    }
  }
}

// ---------------------------------------------------------------------------
// QKV GEMMs, fused in grid.z: z=0 Q=x1@Wq^T, z=1 K=x2@Wk^T,
// z=2 V^T = Wv x2^T (operand-swapped so stores into [B,H,K,W] coalesce).
// Outputs bf16. grid=(32,8,3).  (round-4 byte-identical)
// ---------------------------------------------------------------------------
__global__ __launch_bounds__(256, 3) void gemm_qkv_kernel(
    const short* __restrict__ x1b, const short* __restrict__ x2b,
    const short* __restrict__ wqt, const short* __restrict__ wkt,
    const short* __restrict__ wvt,
    short* __restrict__ qb, short* __restrict__ kb, short* __restrict__ vtb) {
  __shared__ short As[128 * 64], Bs[128 * 64];
  int z = blockIdx.z;
  const short *A, *Bt;
  int arow0, brow0;
  if (z == 0)      { A = x1b; Bt = wqt; arow0 = blockIdx.x * 128; brow0 = blockIdx.y * 128; }
  else if (z == 1) { A = x2b; Bt = wkt; arow0 = blockIdx.x * 128; brow0 = blockIdx.y * 128; }
  else             { A = wvt; Bt = x2b; arow0 = blockIdx.y * 128; brow0 = blockIdx.x * 128; }

  float4v acc[4][4];
  gemm_core(A, Bt, arow0, brow0, As, Bs, acc);

  int wave = threadIdx.x >> 6, lane = threadIdx.x & 63;
  int wr = wave >> 1, wc = wave & 1, lg = lane >> 4, ll = lane & 15;
  if (z <= 1) {
    short* O = (z == 0) ? qb : kb;
    #pragma unroll
    for (int mi = 0; mi < 4; ++mi)
      #pragma unroll
      for (int ni = 0; ni < 4; ++ni) {
        int n = brow0 + wc * 64 + ni * 16 + ll;       // h*64+k
        int h = n >> 6, kk = n & 63;
        #pragma unroll
        for (int r2 = 0; r2 < 4; ++r2) {
          int m = arow0 + wr * 64 + mi * 16 + lg * 4 + r2;  // seq index
          int b = m >> 11, w = m & (W_ - 1);
          O[((size_t)(b * H_ + h) * W_ + w) * K_ + kk] = (short)f2bf(acc[mi][ni][r2]);
        }
      }
  } else {
    #pragma unroll
    for (int mi = 0; mi < 4; ++mi)
      #pragma unroll
      for (int ni = 0; ni < 4; ++ni) {
        int n = brow0 + wc * 64 + ni * 16 + ll;       // seq index
        int b = n >> 11, w = n & (W_ - 1);
        #pragma unroll
        for (int r2 = 0; r2 < 4; ++r2) {
          int m = arow0 + wr * 64 + mi * 16 + lg * 4 + r2;  // h*64+k
          int h = m >> 6, kk = m & 63;
          vtb[((size_t)(b * H_ + h) * K_ + kk) * W_ + w] = (short)f2bf(acc[mi][ni][r2]);
        }
      }
  }
}

// ---------------------------------------------------------------------------
// Mixer GEMM: out[4096,1024] fp32 = attnb @ wmb^T + bias. grid=(64,8)=512
// blocks = 2/CU. (round-4 proven)
// ---------------------------------------------------------------------------
__global__ __launch_bounds__(256, 3) void gemm_mix_kernel(
    const short* __restrict__ attnb, const short* __restrict__ wmb,
    const float* __restrict__ bias, float* __restrict__ out) {
  __shared__ short As[64 * 64], Bs[128 * 64];
  int arow0 = blockIdx.x * 64, brow0 = blockIdx.y * 128;
  float4v acc[2][4];
  gemm_core64(attnb, wmb, arow0, brow0, As, Bs, acc);

  int wave = threadIdx.x >> 6, lane = threadIdx.x & 63;
  int wr = wave >> 1, wc = wave & 1, lg = lane >> 4, ll = lane & 15;
  #pragma unroll
  for (int mi = 0; mi < 2; ++mi)
    #pragma unroll
    for (int ni = 0; ni < 4; ++ni) {
      int n = brow0 + wc * 64 + ni * 16 + ll;
      float bv = bias[n];
      #pragma unroll
      for (int r2 = 0; r2 < 4; ++r2) {
        int m = arow0 + wr * 32 + mi * 16 + lg * 4 + r2;
        out[(size_t)m * C_ + n] = acc[mi][ni][r2] + bv;
      }
    }
}

// ---------------------------------------------------------------------------
// Causal flash attention — round-6 proven kernel (64-q tile, 1024 blocks,
// swapped-operand softmax, ones-MFMA lsum, max3, setprio) with ONE change:
// single-buffered V -> LDS 41984 -> 33792 B -> 4 blocks/CU (was 3).
// Round 7's 128-q tile regressed (occupancy collapse 22.7->12%: 2 blocks/CU,
// no backfill after the light block retires) — reverted.
// The single-V schedule was round 2's; its failure is now attributed solely
// to cvt_pk (round 5 failed WITH dual-buffer+cvt_pk; round 6 passed without
// cvt_pk). Hazard ledger re-verified:
//   top:  STAGE_K(t+1) [2 loads]; vmcnt(2)+barrier
//         -> per-wave outstanding {K(t),V(t),K(t+1)}; wait leaves K(t+1)
//         -> K(t),V(t) landed for THIS wave before ITS barrier arrival;
//            rendezvous => whole buffer complete for all waves.
//   body: QK^T from Ks[cur]; bv <- Vs (regs); mask; max/rescale
//   mid:  lgkmcnt(0)+barrier (drains all Ks[cur]+Vs reads, all waves);
//         STAGE_V(t+1) -> safe Vs overwrite; K(t+2) write to Ks[cur] at next
//         top is also safe (issued only after this rendezvous).
//   P-phase + PV; NO end-of-loop barrier needed (mid replaced it; 2/iter).
// (256,4): VGPR cap 128 vs measured 68 -> no spill, vmcnt counting sound.
// ---------------------------------------------------------------------------
__global__ __launch_bounds__(256, 4) void attn_mfma_kernel(
    const short* __restrict__ q, const short* __restrict__ k,
    const short* __restrict__ vt, short* __restrict__ out) {
  int bh = blockIdx.x;                    // 0..31
  int b = bh >> 4, h = bh & 15;
  int s = blockIdx.y;
  int qt = (s < 16) ? (31 - s) : (s - 16);  // balanced heavy/light pairing
  int wave = threadIdx.x >> 6;
  int lane = threadIdx.x & 63;
  int lg = lane >> 4, ll = lane & 15;

  __shared__ short Ks[2][64 * 64];        // [key][chan], swizzled chunks
  __shared__ short Vs[64 * 64];           // [chan][key], swizzled, single buf
  __shared__ short Ps[4][16 * 72];        // per-wave P buffer [q][key(+pad)]

  const short* qp = q + (size_t)bh * W_ * K_;
  const short* kp = k + (size_t)bh * W_ * K_;
  const short* vb = vt + (size_t)bh * K_ * W_;

  // Q B-frags: this lane's q row is qt*64 + wave*16 + ll (frag col = ll)
  int qrow = qt * 64 + wave * 16 + ll;
  short8 aq[2];
  #pragma unroll
  for (int kc = 0; kc < 2; ++kc)
    aq[kc] = *(const short8*)(qp + (size_t)qrow * K_ + kc * 32 + lg * 8);

  short8 ones;                            // bf16 1.0 x8, A-frag for l-sum MFMA
  #pragma unroll
  for (int i = 0; i < 8; ++i) ones[i] = (short)0x3F80;

  float4v o[4];                           // O^T: o[ct][r] = O[q=ll][ct*16+lg*4+r]
  #pragma unroll
  for (int ct = 0; ct < 4; ++ct) {
    o[ct][0] = 0.f; o[ct][1] = 0.f; o[ct][2] = 0.f; o[ct][3] = 0.f;
  }
  float4v lsum;                           // every reg = sum_k P[q][k]
  lsum[0] = 0.f; lsum[1] = 0.f; lsum[2] = 0.f; lsum[3] = 0.f;
  float m = -INFINITY;                    // per-lane scalar running max (one q)

  int nkt = qt + 1;

  #define STAGE_K(kt, buf)                                                 \
    {                                                                      \
      const short* kbase = kp + (size_t)(kt) * 64 * K_;                    \
      _Pragma("unroll")                                                    \
      for (int j = 0; j < 2; ++j) {                                        \
        int sdx = j * 256 + (int)threadIdx.x;                              \
        int mm = sdx >> 3, c7 = sdx & 7;                                   \
        int gc = c7 ^ (mm & 7);                                            \
        gload_lds16(kbase + (size_t)mm * K_ + gc * 8, &Ks[buf][sdx * 8]);  \
      }                                                                    \
    }
  #define STAGE_V(kt)                                                     \
    {                                                                      \
      const short* vbase = vb + (kt) * 64;                                 \
      _Pragma("unroll")                                                    \
      for (int j = 0; j < 2; ++j) {                                        \
        int sdx = j * 256 + (int)threadIdx.x;                              \
        int mm = sdx >> 3, c7 = sdx & 7;                                   \
        int gc = c7 ^ (mm & 7);                                            \
        gload_lds16(vbase + (size_t)mm * W_ + gc * 8, &Vs[sdx * 8]);       \
      }                                                                    \
    }

  STAGE_K(0, 0);
  STAGE_V(0);
  for (int kt = 0; kt < nkt; ++kt) {
    int cur = kt & 1;
    if (kt + 1 < nkt) {
      STAGE_K(kt + 1, cur ^ 1);
      // wait K(kt)+V(kt) only; K(kt+1) prefetch stays in flight
      asm volatile("s_waitcnt vmcnt(2)\ns_barrier" ::: "memory");
    } else {
      asm volatile("s_waitcnt vmcnt(0)\ns_barrier" ::: "memory");
    }

    // ---- S^T = K.Q^T : st[nt][r] = S[q=ll][key = kt*64 + nt*16 + lg*4 + r]
    float4v st[4];
    __builtin_amdgcn_s_setprio(1);
    #pragma unroll
    for (int nt = 0; nt < 4; ++nt) {
      st[nt][0] = 0.f; st[nt][1] = 0.f; st[nt][2] = 0.f; st[nt][3] = 0.f;
      int n = nt * 16 + ll;               // key frag index (A operand)
      #pragma unroll
      for (int kc = 0; kc < 2; ++kc) {
        int cc = kc * 4 + lg;
        short8 bk = *(const short8*)&Ks[cur][n * 64 + ((cc ^ (n & 7)) << 3)];
        st[nt] = __builtin_amdgcn_mfma_f32_16x16x32_bf16(bk, aq[kc], st[nt], 0, 0, 0);
      }
    }
    __builtin_amdgcn_s_setprio(0);

    // ---- V^T frags into registers (before mid barrier releases Vs) ----
    short8 bv[4][2];
    #pragma unroll
    for (int ct = 0; ct < 4; ++ct) {
      int c = ct * 16 + ll;
      #pragma unroll
      for (int kc = 0; kc < 2; ++kc) {
        int cc = kc * 4 + lg;
        bv[ct][kc] = *(const short8*)&Vs[c * 64 + ((cc ^ (c & 7)) << 3)];
      }
    }

    if (kt == qt) {  // diagonal tile: causal mask (key > q)
      #pragma unroll
      for (int nt = 0; nt < 4; ++nt) {
        int keyb = nt * 16 + lg * 4;      // key within tile
        #pragma unroll
        for (int r = 0; r < 4; ++r)
          if (keyb + r > wave * 16 + ll) st[nt][r] = -INFINITY;
      }
    }

    // ---- row max (per-lane scalar stats), max3-shaped tree ----
    float ma = max3f(st[0][0], st[0][1], st[0][2]);
    float mb = max3f(st[0][3], st[1][0], st[1][1]);
    float mc = max3f(st[1][2], st[1][3], st[2][0]);
    float md = max3f(st[2][1], st[2][2], st[2][3]);
    float me = max3f(st[3][0], st[3][1], st[3][2]);
    float lm = fmaxf(max3f(ma, mb, mc), max3f(md, me, st[3][3]));
    lm = fmaxf(lm, __shfl_xor(lm, 16, 64));
    lm = fmaxf(lm, __shfl_xor(lm, 32, 64));
    if (!__all(lm <= m + 8.f)) {          // defer-max: rescale only on growth
      float nm = fmaxf(m, lm);
      float al = EXP2(m - nm);            // first tile: exp2(-inf) = 0
      m = nm;
      lsum[0] *= al; lsum[1] *= al; lsum[2] *= al; lsum[3] *= al;
      #pragma unroll
      for (int ct = 0; ct < 4; ++ct) {
        o[ct][0] *= al; o[ct][1] *= al; o[ct][2] *= al; o[ct][3] *= al;
      }
    }

    // ---- mid barrier: all Ks[cur]+Vs reads drained -> restage V ----
    if (kt + 1 < nkt) {
      asm volatile("s_waitcnt lgkmcnt(0)\ns_barrier" ::: "memory");
      STAGE_V(kt + 1);
    }

    // ---- P = exp2(S - m) -> bf16 (f2bf) -> wave-private LDS ----
    float p[4][4];
    #pragma unroll
    for (int nt = 0; nt < 4; ++nt)
      #pragma unroll
      for (int r = 0; r < 4; ++r)
        p[nt][r] = EXP2(st[nt][r] - m);

    short* myP = &Ps[wave][ll * 72];
    #pragma unroll
    for (int nt = 0; nt < 4; ++nt) {
      uint2 w;
      w.x = (unsigned)f2bf(p[nt][0]) | ((unsigned)f2bf(p[nt][1]) << 16);
      w.y = (unsigned)f2bf(p[nt][2]) | ((unsigned)f2bf(p[nt][3]) << 16);
      *(uint2*)(myP + nt * 16 + lg * 4) = w;
    }
    __builtin_amdgcn_s_waitcnt(0xC07F);  // lgkmcnt(0), wave-private
    short8 bp0 = *(const short8*)(myP + lg * 8);        // keys lg*8..+7
    short8 bp1 = *(const short8*)(myP + 32 + lg * 8);   // keys 32+lg*8..+7

    // ---- O^T += V^T.P^T ; l += ones.P^T (row-sum via MFMA) ----
    __builtin_amdgcn_s_setprio(1);
    lsum = __builtin_amdgcn_mfma_f32_16x16x32_bf16(ones, bp0, lsum, 0, 0, 0);
    lsum = __builtin_amdgcn_mfma_f32_16x16x32_bf16(ones, bp1, lsum, 0, 0, 0);
    #pragma unroll
    for (int ct = 0; ct < 4; ++ct) {
      o[ct] = __builtin_amdgcn_mfma_f32_16x16x32_bf16(bv[ct][0], bp0, o[ct], 0, 0, 0);
      o[ct] = __builtin_amdgcn_mfma_f32_16x16x32_bf16(bv[ct][1], bp1, o[ct], 0, 0, 0);
    }
    __builtin_amdgcn_s_setprio(0);
    // no end-of-loop barrier: the mid lgkmcnt(0)+barrier already fenced the
    // buffer reuse for the next iteration.
  }
  #undef STAGE_K
  #undef STAGE_V

  // ---- epilogue: normalize (lane-local), write bf16 [B,W,C] as 8B packs ----
  float invl = 1.0f / lsum[0];
  size_t orow = ((size_t)(b * W_ + qrow)) * C_ + h * K_;
  #pragma unroll
  for (int ct = 0; ct < 4; ++ct) {
    uint2 w;
    w.x = (unsigned)f2bf(o[ct][0] * invl) | ((unsigned)f2bf(o[ct][1] * invl) << 16);
    w.y = (unsigned)f2bf(o[ct][2] * invl) | ((unsigned)f2bf(o[ct][3] * invl) << 16);
    *(uint2*)(out + orow + ct * 16 + lg * 4) = w;
  }
}

// ---------------------------------------------------------------------------
extern "C" void kernel_launch(void* const* d_in, const int* in_sizes, int n_in,
                              void* d_out, int out_size, void* d_ws, size_t ws_size,
                              hipStream_t stream) {
  const float* seq1  = (const float*)d_in[0];
  const float* seq2  = (const float*)d_in[1];
  const float* gamma = (const float*)d_in[2];
  const float* beta  = (const float*)d_in[3];
  const float* qp    = (const float*)d_in[4];
  const float* kp    = (const float*)d_in[5];
  const float* vp    = (const float*)d_in[6];
  const float* wm    = (const float*)d_in[7];
  const float* mb    = (const float*)d_in[8];
  float* out = (float*)d_out;

  char* ws = (char*)d_ws;
  const size_t NROW = (size_t)B_ * W_;               // 4096
  const size_t XB = NROW * C_ * sizeof(short);       // 8 MB bf16 activation buf
  const size_t WB = (size_t)C_ * C_ * sizeof(short); // 2 MB bf16 weight buf
  short* x1b = (short*)(ws);
  short* x2b = (short*)(ws + XB);
  short* qb  = (short*)(ws + 2 * XB);
  short* kb  = (short*)(ws + 3 * XB);
  short* vtb = (short*)(ws + 4 * XB);
  short* wqt = (short*)(ws + 5 * XB);
  short* wkt = (short*)(ws + 5 * XB + WB);
  short* wvt = (short*)(ws + 5 * XB + 2 * WB);
  short* wmb = (short*)(ws + 5 * XB + 3 * WB);
  short* attnb = (short*)(ws + 5 * XB + 4 * WB);

  wprep_proj_kernel<<<dim3(C_ / 64, H_, 3), dim3(256), 0, stream>>>(
      qp, kp, vp, wqt, wkt, wvt);
  wprep_mix_kernel<<<dim3(C_ * C_ / 1024), dim3(256), 0, stream>>>(wm, wmb);
  ln_kernel<<<dim3(2 * (unsigned)NROW), dim3(256), 0, stream>>>(
      seq1, seq2, gamma, beta, x1b, x2b);
  gemm_qkv_kernel<<<dim3(32, 8, 3), dim3(256), 0, stream>>>(
      x1b, x2b, wqt, wkt, wvt, qb, kb, vtb);
  attn_mfma_kernel<<<dim3(32, 32), dim3(256), 0, stream>>>(
      qb, kb, vtb, attnb);
  gemm_mix_kernel<<<dim3(64, 8), dim3(256), 0, stream>>>(attnb, wmb, mb, out);
}